// Round 16
// baseline (5306.158 us; speedup 1.0000x reference)
//
#include <hip/hip_runtime.h>
#include <hip/hip_fp16.h>

typedef unsigned short u16;
typedef _Float16 f16x8 __attribute__((ext_vector_type(8)));
typedef float f32x4 __attribute__((ext_vector_type(4)));

#define VV   96
#define DD   256
#define NSL  24
#define HH   512
#define LL   2
#define BB   64
#define TT   128

// ---- workspace byte layout (after 3,481,600 B of f16 weights) ----
#define EXB    3489792u           // exchange region base
#define SBYT   45056u             // per-batch exchange stride
#define OF_R2P 0u                 // [2][4][24] f32
#define OF_PJP 1024u              // [2][4][256] f32
#define OF_F2P 9216u              // [2][4][256] f32
#define OF_SM  17408u             // [2][256] f32
#define OF_S16 19456u             // [2][24][128] dwords (f16 pairs)
#define OF_FLAGS (EXB + 64u*SBYT) // 256 u32

#define AG_ST(p,v) __hip_atomic_store((p),(v),__ATOMIC_RELAXED,__HIP_MEMORY_SCOPE_AGENT)
#define AG_LD(p)   __hip_atomic_load((p),__ATOMIC_RELAXED,__HIP_MEMORY_SCOPE_AGENT)

__device__ __forceinline__ u16 f2h(float f){ return __half_as_ushort(__float2half(f)); }
__device__ __forceinline__ float gelu_f(float x){ return 0.5f*x*(1.f+erff(x*0.70710678118654752f)); }
__device__ __forceinline__ float sigm_f(float x){ return 1.f/(1.f+__expf(-x)); }
__device__ __forceinline__ float tanh_f(float x){
  x = fminf(15.f, fmaxf(-15.f, x));
  float e2 = __expf(2.f*x);
  return (e2-1.f)/(e2+1.f);
}

__device__ __forceinline__ float dotg8(const u16* __restrict__ row, const float* __restrict__ v,
                                       int g, int iters){
  float acc = 0.f;
  #pragma unroll
  for(int it=0; it<iters; ++it){
    int k = (it*8 + g)*8;
    uint4 w = *(const uint4*)(row + k);
    float4 a  = *(const float4*)(v + k);
    float4 bq = *(const float4*)(v + k + 4);
    float2 f0 = __half22float2(*(const __half2*)&w.x);
    float2 f1 = __half22float2(*(const __half2*)&w.y);
    float2 f2_ = __half22float2(*(const __half2*)&w.z);
    float2 f3 = __half22float2(*(const __half2*)&w.w);
    acc += f0.x*a.x + f0.y*a.y + f1.x*a.z + f1.y*a.w;
    acc += f2_.x*bq.x + f2_.y*bq.y + f3.x*bq.z + f3.y*bq.w;
  }
  return acc;
}
__device__ __forceinline__ float dotg16(const u16* __restrict__ row, const float* __restrict__ v,
                                        int tl, int iters){
  float acc = 0.f;
  #pragma unroll
  for(int it=0; it<iters; ++it){
    int k = (it*16 + tl)*8;
    uint4 w = *(const uint4*)(row + k);
    float4 a  = *(const float4*)(v + k);
    float4 bq = *(const float4*)(v + k + 4);
    float2 f0 = __half22float2(*(const __half2*)&w.x);
    float2 f1 = __half22float2(*(const __half2*)&w.y);
    float2 f2_ = __half22float2(*(const __half2*)&w.z);
    float2 f3 = __half22float2(*(const __half2*)&w.w);
    acc += f0.x*a.x + f0.y*a.y + f1.x*a.z + f1.y*a.w;
    acc += f2_.x*bq.x + f2_.y*bq.y + f3.x*bq.z + f3.y*bq.w;
  }
  return acc;
}
__device__ __forceinline__ float red8(float a){
  a += __shfl_down(a,4,64); a += __shfl_down(a,2,64); a += __shfl_down(a,1,64);
  return a;
}
__device__ __forceinline__ float red16(float a){
  a += __shfl_down(a,8,64); a += __shfl_down(a,4,64);
  a += __shfl_down(a,2,64); a += __shfl_down(a,1,64);
  return a;
}

// Batched-poll 4-WG barrier (R13-proven): 3 independent peer loads per round.
__device__ __forceinline__ void syncq(unsigned* flags, int b, int c, unsigned ep, int tid){
  __syncthreads();
  if(tid==0){
    AG_ST(&flags[b*4+c], ep);
    const int p0=(c+1)&3, p1=(c+2)&3, p2=(c+3)&3;
    for(;;){
      unsigned a0 = AG_LD(&flags[b*4+p0]);
      unsigned a1 = AG_LD(&flags[b*4+p1]);
      unsigned a2 = AG_LD(&flags[b*4+p2]);
      if(a0>=ep && a1>=ep && a2>=ep) break;
      __builtin_amdgcn_s_sleep(2);
    }
  }
  __syncthreads();
}
// Split barrier: arrive = drain + publish (no wait); wait = poll + block barrier.
// RULE (R14 lesson): NO cross-WG publishes between arrive and wait — only
// local LDS writes / register loads in the hidden window.
__device__ __forceinline__ void syncq_arrive(unsigned* flags, int b, int c, unsigned ep, int tid){
  __syncthreads();                    // all prior payload stores drained
  if(tid==0) AG_ST(&flags[b*4+c], ep);
}
__device__ __forceinline__ void syncq_wait(unsigned* flags, int b, int c, unsigned ep, int tid){
  if(tid==0){
    const int p0=(c+1)&3, p1=(c+2)&3, p2=(c+3)&3;
    for(;;){
      unsigned a0 = AG_LD(&flags[b*4+p0]);
      unsigned a1 = AG_LD(&flags[b*4+p1]);
      unsigned a2 = AG_LD(&flags[b*4+p2]);
      if(a0>=ep && a1>=ep && a2>=ep) break;
      __builtin_amdgcn_s_sleep(2);
    }
  }
  __syncthreads();
}

// ---------- prep kernels ----------
__global__ void k_cvt(const float* __restrict__ s, u16* __restrict__ d, int n){
  int i = blockIdx.x*256 + threadIdx.x;
  if(i<n) d[i] = f2h(s[i]);
}
__global__ void k_cvtT(const float* __restrict__ s, u16* __restrict__ d, int K, int N){
  int i = blockIdx.x*256 + threadIdx.x;
  if(i < K*N){ int k = i/N, n = i - k*N; d[n*K + k] = f2h(s[i]); }
}
__global__ void k_zeroflags(unsigned* f){ f[threadIdx.x] = 0u; }

__global__ __launch_bounds__(1024, 4) void ssr_main(
    const int* __restrict__ x, const float* __restrict__ emb, const float* __restrict__ pos,
    const u16* __restrict__ r1T, const float* __restrict__ b_r1,
    const u16* __restrict__ r2T, const float* __restrict__ b_r2,
    const u16* __restrict__ wihW, const u16* __restrict__ whhW,
    const float* __restrict__ bih, const float* __restrict__ bhh,
    const u16* __restrict__ pjT, const float* __restrict__ b_pj,
    const float* __restrict__ g1, const float* __restrict__ be1,
    const u16* __restrict__ f1T, const float* __restrict__ b_f1,
    const u16* __restrict__ f2T, const float* __restrict__ b_f2,
    const float* __restrict__ g2, const float* __restrict__ be2,
    const float* __restrict__ go, const float* __restrict__ bo,
    const u16* __restrict__ hdT, const float* __restrict__ b_hd,
    void* __restrict__ wsraw,
    float* __restrict__ out)
{
  extern __shared__ float sm[];
  float* S_l   = sm;                  // [2][24][64] fp32 sharded slot state
  u16*  sbf0   = (u16*)(sm + 3072);   // [32][264] f16 full S, layer 0
  u16*  sbf1   = (u16*)(sm + 7296);   // [32][264] f16 full S, layer 1
  float* gh_l  = sm + 11520;          // [24][200] f32 local gh (own e-set)
  float* gx_l  = sm + 16320;          // 192
  float* xv    = sm + 16512;          // 256
  float* smean = sm + 16768;          // [2][256] slot means (double-buffered)
  float* xm    = sm + 17280;          // 256
  float* h1    = sm + 17536;          // 256
  float* hmid_l= sm + 17792;          // 64
  float* ff_l  = sm + 17856;          // 128
  float* sctx  = sm + 17984;          // 64
  float* alpha = sm + 18048;          // 32
  float* red   = sm + 18080;          // 64
  float* pc    = sm + 18144;          // 1024
  // total 19168 floats = 76672 B

  const int wgid = blockIdx.x;
  const int b = wgid & 63;
  const int c = wgid >> 6;           // d-quarter index 0..3
  const int tid = threadIdx.x;
  const int g = tid & 7,  gid = tid >> 3;   // 128 groups of 8
  const int tl = tid & 15, tm = tid >> 4;   // 64 teams of 16

  char* exb = (char*)wsraw + EXB + (size_t)b*SBYT;
  float*    ex_r2p = (float*)(exb + OF_R2P);
  float*    ex_pjp = (float*)(exb + OF_PJP);
  float*    ex_f2p = (float*)(exb + OF_F2P);
  float*    ex_sm  = (float*)(exb + OF_SM);
  unsigned* ex_s16 = (unsigned*)(exb + OF_S16);
  unsigned* flags  = (unsigned*)((char*)wsraw + OF_FLAGS);
  unsigned ep = 0;

  for(int i=tid;i<19168;i+=1024) sm[i]=0.f;   // zeros S_l, sbf0/1, smean (t=0 state)
  __syncthreads();

  for(int t=0;t<TT;++t){
    const int tok = x[b*TT + t];
    if(tid<DD) xv[tid] = emb[tok*DD+tid] + pos[t*DD+tid];
    __syncthreads();

    for(int li=0; li<LL; ++li){
      u16* sbf = li ? sbf1 : sbf0;
      const float* smeanL = smean + li*DD;

      // ---- route1 (N-split): own 64 rows, K=512 = [xv | smeanL] (prefetched)
      {
        const u16* row = r1T + (size_t)(li*DD + c*64 + tm)*(2*DD);
        float a = dotg16(row, xv, tl, 2) + dotg16(row + 256, smeanL, tl, 2);
        a = red16(a);
        if(!tl) hmid_l[tm] = gelu_f(a + b_r1[li*DD + c*64 + tm]);
      }
      __syncthreads();
      // ---- route2 partials (own hmid slice) -> publish, then ARRIVE
      if(gid < NSL){
        const u16* row = r2T + (size_t)(li*NSL + gid)*DD + c*64;
        float a = red8(dotg8(row, hmid_l, g, 1));
        if(!g) AG_ST(&ex_r2p[li*96 + c*24 + gid], a);
      }
      ++ep;
      syncq_arrive(flags, b, c, ep, tid);     // r2 stores drained + flag up
      // ---- hidden window #1: gx + MFMA + next-layer S/smean gather (all local)
      {
        const u16* W = wihW + (size_t)li*3*DD*DD;
        for(int le=gid; le<192; le+=128){
          int e = (le>>6)*DD + c*64 + (le&63);
          float a = red8(dotg8(W + (size_t)e*DD, xv, g, 4));
          if(!g) gx_l[le] = a;
        }
      }
      {
        const int lane = tid & 63, w = tid >> 6;
        if(w < 12){
          const int lr = lane & 15, lk = lane >> 4;
          const int q = w >> 2, j = w & 3;
          const u16* WB = whhW + (size_t)li*3*DD*DD;
          const u16* a0p = sbf + lr*264 + lk*8;
          const u16* a1p = sbf + (16+lr)*264 + lk*8;
          const u16* bp = WB + (size_t)(q*DD + c*64 + j*16 + lr)*DD + lk*8;
          f32x4 acc0 = {0.f,0.f,0.f,0.f}, acc1 = {0.f,0.f,0.f,0.f};
          #pragma unroll
          for(int ks=0; ks<8; ++ks){
            f16x8 bfr = *(const f16x8*)(bp + ks*32);
            f16x8 a0  = *(const f16x8*)(a0p + ks*32);
            f16x8 a1  = *(const f16x8*)(a1p + ks*32);
            acc0 = __builtin_amdgcn_mfma_f32_16x16x32_f16(a0, bfr, acc0, 0,0,0);
            acc1 = __builtin_amdgcn_mfma_f32_16x16x32_f16(a1, bfr, acc1, 0,0,0);
          }
          int le = q*64 + j*16 + lr;
          #pragma unroll
          for(int r=0;r<4;++r){
            int s0 = lk*4 + r;
            gh_l[s0*200 + le] = acc0[r];
            int s1 = 16 + lk*4 + r;
            if(s1 < NSL) gh_l[s1*200 + le] = acc1[r];
          }
        }
      }
      // prefetch gather for the NEXT layer's consumer (LDS-local writes only):
      //  li=0: S16(li=1)+sm(li=1) published at t-1 (skip at t=0: zeros = S0)
      //  li=1: S16(li=0)+sm(li=0) published THIS step (sealed by full syncq#2(li=0))
      if(li==0){
        if(t>0){
          for(int i=tid;i<3072;i+=1024){
            int s_=i>>7, dw=i&127;
            unsigned d32 = AG_LD(&ex_s16[3072+i]);
            *(unsigned*)(sbf1 + s_*264 + dw*2) = d32;
          }
          if(tid<DD) smean[DD+tid] = AG_LD(&ex_sm[DD+tid]);
        }
      } else {
        for(int i=tid;i<3072;i+=1024){
          int s_=i>>7, dw=i&127;
          unsigned d32 = AG_LD(&ex_s16[i]);
          *(unsigned*)(sbf0 + s_*264 + dw*2) = d32;
        }
        if(tid<DD) smean[tid] = AG_LD(&ex_sm[tid]);
      }
      syncq_wait(flags, b, c, ep, tid);       // peers' r2 partials visible
      // ---- alpha: fused 32-lane gather + softmax (replicated-identical)
      if(tid < 32){
        float lg = -1e30f;
        if(tid < NSL){
          lg = b_r2[li*NSL+tid];
          #pragma unroll
          for(int cc=0;cc<4;++cc) lg += AG_LD(&ex_r2p[li*96 + cc*24 + tid]);
        }
        float m = lg;
        #pragma unroll
        for(int o=16;o>0;o>>=1) m = fmaxf(m, __shfl_xor(m,o,32));
        float e = (tid<NSL) ? __expf(lg-m) : 0.f;
        float s = e;
        #pragma unroll
        for(int o=16;o>0;o>>=1) s += __shfl_xor(s,o,32);
        if(tid<NSL) alpha[tid] = e/s;
      }
      __syncthreads();
      // ---- GRU update (own d-quarter, all 24 slots): all local
      {
        int dd = tid & 63, sg = tid >> 6;
        int dg = li*3*DD + c*64 + dd;
        float gir = gx_l[dd],      bir = bih[dg],        bhr = bhh[dg];
        float giz = gx_l[64+dd],   biz = bih[dg+DD],     bhz = bhh[dg+DD];
        float gin = gx_l[128+dd],  bin = bih[dg+2*DD],   bhn = bhh[dg+2*DD];
        float pctx = 0.f;
        float* Sll = S_l + li*NSL*64;
        #pragma unroll
        for(int h=0;h<2;++h){
          int s_ = sg + h*16;
          if(s_ < NSL){
            float al = alpha[s_];
            float hr = gh_l[s_*200 + dd]       + bhr;
            float hz = gh_l[s_*200 + 64 + dd]  + bhz;
            float hn = gh_l[s_*200 + 128 + dd] + bhn;
            float rr = sigm_f(al*gir + bir + hr);
            float zz = sigm_f(al*giz + biz + hz);
            float nn = tanh_f(al*gin + bin + rr*hn);
            float sv = Sll[s_*64+dd];
            float ns = (1.f-zz)*nn + zz*sv;
            Sll[s_*64+dd] = ns;
            pctx += al*ns;
          }
        }
        pc[tid] = pctx;
      }
      __syncthreads();
      if(tid<64){
        float s_=0.f;
        #pragma unroll
        for(int k=0;k<16;++k) s_ += pc[k*64+tid];
        sctx[tid] = s_;
        float m_=0.f;
        const float* Sll = S_l + li*NSL*64;
        #pragma unroll
        for(int s2=0;s2<NSL;++s2) m_ += Sll[s2*64+tid];
        AG_ST(&ex_sm[li*DD + c*64 + tid], m_*(1.f/NSL));
      }
      __syncthreads();
      // ---- publish S_new (f16 pairs) + proj partials  (R13/R15 position)
      for(int i=tid;i<768;i+=1024){
        int s_ = i>>5, dp = (i&31)*2;
        const float* Sll = S_l + li*NSL*64;
        unsigned lo = (unsigned)f2h(Sll[s_*64+dp]);
        unsigned hi = (unsigned)f2h(Sll[s_*64+dp+1]);
        AG_ST(&ex_s16[li*3072 + s_*128 + c*32 + (i&31)], lo | (hi<<16));
      }
      {
        #pragma unroll
        for(int p=0;p<2;++p){
          int dout = p*128 + gid;
          const u16* row = pjT + (size_t)(li*DD + dout)*DD + c*64;
          float a = red8(dotg8(row, sctx, g, 1));
          if(!g) AG_ST(&ex_pjp[li*1024 + c*256 + dout], a);
        }
      }
      ++ep;
      syncq_arrive(flags, b, c, ep, tid);     // S16, sm, pjp drained + flag up
      // ---- hidden window #2: ffn1 weight prefetch into VGPRs (local loads only)
      uint4 wf[4];
      if(gid < 128){
        const u16* frow = f1T + (size_t)(li*HH + c*128 + gid)*DD;
        #pragma unroll
        for(int it=0;it<4;++it) wf[it] = *(const uint4*)(frow + (it*8+g)*8);
      }
      syncq_wait(flags, b, c, ep, tid);       // peers' proj partials visible
      // ---- fused xm + LN1 (2 barriers)
      {
        float v = 0.f;
        if(tid<DD){
          float s_ = b_pj[li*DD+tid];
          #pragma unroll
          for(int cc=0;cc<4;++cc) s_ += AG_LD(&ex_pjp[li*1024 + cc*256 + tid]);
          v = xv[tid] + s_;
          xm[tid] = v;
        }
        float s1 = (tid<DD)?v:0.f, s2 = (tid<DD)?v*v:0.f;
        #pragma unroll
        for(int o=32;o>0;o>>=1){ s1 += __shfl_xor(s1,o,64); s2 += __shfl_xor(s2,o,64); }
        if(tid<DD && (tid&63)==0){ red[tid>>6]=s1; red[8+(tid>>6)]=s2; }
        __syncthreads();
        if(tid<DD){
          float a = red[0]+red[1]+red[2]+red[3];
          float cs= red[8]+red[9]+red[10]+red[11];
          float m = a*(1.f/DD), rs = rsqrtf(cs*(1.f/DD) - m*m + 1e-5f);
          h1[tid] = (v-m)*rs*g1[li*DD+tid] + be1[li*DD+tid];
        }
        __syncthreads();
      }
      // ---- ffn1 (N-split, local): own 128 rows, K=256, weights already in regs
      if(gid < 128){
        float acc = 0.f;
        #pragma unroll
        for(int it=0;it<4;++it){
          int k = (it*8+g)*8;
          float4 a4 = *(const float4*)(h1 + k);
          float4 b4 = *(const float4*)(h1 + k + 4);
          float2 f0 = __half22float2(*(const __half2*)&wf[it].x);
          float2 f1v = __half22float2(*(const __half2*)&wf[it].y);
          float2 f2v = __half22float2(*(const __half2*)&wf[it].z);
          float2 f3v = __half22float2(*(const __half2*)&wf[it].w);
          acc += f0.x*a4.x + f0.y*a4.y + f1v.x*a4.z + f1v.y*a4.w;
          acc += f2v.x*b4.x + f2v.y*b4.y + f3v.x*b4.z + f3v.y*b4.w;
        }
        acc = red8(acc);
        if(!g) ff_l[gid] = gelu_f(acc + b_f1[li*HH + c*128 + gid]);
      }
      __syncthreads();
      // ---- ffn2 partials (K-split over own ff 128-slice)
      {
        #pragma unroll
        for(int p=0;p<4;++p){
          int dout = p*64 + tm;
          const u16* row = f2T + (size_t)(li*DD + dout)*HH + c*128;
          float a = red16(dotg16(row, ff_l, tl, 1));
          if(!tl) AG_ST(&ex_f2p[li*1024 + c*256 + dout], a);
        }
      }
      syncq(flags, b, c, ++ep, tid);          // ffn2 partials
      // ---- fused xm2 + LN2 -> xv (2 barriers)
      {
        float v = 0.f;
        if(tid<DD){
          float s_ = b_f2[li*DD+tid];
          #pragma unroll
          for(int cc=0;cc<4;++cc) s_ += AG_LD(&ex_f2p[li*1024 + cc*256 + tid]);
          v = xm[tid] + s_;
        }
        float s1 = (tid<DD)?v:0.f, s2 = (tid<DD)?v*v:0.f;
        #pragma unroll
        for(int o=32;o>0;o>>=1){ s1 += __shfl_xor(s1,o,64); s2 += __shfl_xor(s2,o,64); }
        if(tid<DD && (tid&63)==0){ red[tid>>6]=s1; red[8+(tid>>6)]=s2; }
        __syncthreads();
        if(tid<DD){
          float a = red[0]+red[1]+red[2]+red[3];
          float cs= red[8]+red[9]+red[10]+red[11];
          float m = a*(1.f/DD), rs = rsqrtf(cs*(1.f/DD) - m*m + 1e-5f);
          xv[tid] = (v-m)*rs*g2[li*DD+tid] + be2[li*DD+tid];
        }
        __syncthreads();
      }
    } // layers

    // ---- head: fused LN (2 barriers) + own 24 rows GEMV
    {
      float v = (tid<DD) ? xv[tid] : 0.f;
      float s1 = v, s2 = v*v;
      #pragma unroll
      for(int o=32;o>0;o>>=1){ s1 += __shfl_xor(s1,o,64); s2 += __shfl_xor(s2,o,64); }
      if(tid<DD && (tid&63)==0){ red[tid>>6]=s1; red[8+(tid>>6)]=s2; }
      __syncthreads();
      if(tid<DD){
        float a = red[0]+red[1]+red[2]+red[3];
        float cs= red[8]+red[9]+red[10]+red[11];
        float m = a*(1.f/DD), rs = rsqrtf(cs*(1.f/DD) - m*m + 1e-5f);
        h1[tid] = (v-m)*rs*go[tid] + bo[tid];
      }
      __syncthreads();
    }
    if(gid < NSL){
      int n = c*24 + gid;
      float acc = red8(dotg8(hdT + (size_t)n*DD, h1, g, 4));
      if(!g) out[((size_t)b*TT + t)*VV + n] = acc + b_hd[n];
    }
    __syncthreads();
  }
}

extern "C" void kernel_launch(void* const* d_in, const int* in_sizes, int n_in,
                              void* d_out, int out_size, void* d_ws, size_t ws_size,
                              hipStream_t stream){
  const int*   x    = (const int*)  d_in[0];
  const float* emb  = (const float*)d_in[1];
  const float* pos  = (const float*)d_in[2];
  const float* r1   = (const float*)d_in[3];
  const float* br1  = (const float*)d_in[4];
  const float* r2   = (const float*)d_in[5];
  const float* br2  = (const float*)d_in[6];
  const float* wih  = (const float*)d_in[7];
  const float* whh  = (const float*)d_in[8];
  const float* bih  = (const float*)d_in[9];
  const float* bhh  = (const float*)d_in[10];
  const float* pj   = (const float*)d_in[11];
  const float* bpj  = (const float*)d_in[12];
  const float* g1   = (const float*)d_in[13];
  const float* be1  = (const float*)d_in[14];
  const float* f1   = (const float*)d_in[15];
  const float* bf1  = (const float*)d_in[16];
  const float* f2   = (const float*)d_in[17];
  const float* bf2  = (const float*)d_in[18];
  const float* g2   = (const float*)d_in[19];
  const float* be2  = (const float*)d_in[20];
  const float* go   = (const float*)d_in[21];
  const float* bo   = (const float*)d_in[22];
  const float* hd   = (const float*)d_in[23];
  const float* bhd  = (const float*)d_in[24];
  float* out = (float*)d_out;
  u16* ws = (u16*)d_ws;

  // f16 weight sections in workspace (u16 element offsets)
  u16* r1T  = ws + 0;        // L*256*512
  u16* r2T  = ws + 262144;   // L*24*256
  u16* wihW = ws + 274432;   // L*768*256
  u16* whhW = ws + 667648;   // L*768*256
  u16* pjT  = ws + 1060864;  // L*256*256
  u16* f1T  = ws + 1191936;  // L*512*256
  u16* f2T  = ws + 1454080;  // L*256*512
  u16* hdT  = ws + 1716224;  // 96*256 -> weights end 3,481,600 B

  k_cvt<<<(2*768*256+255)/256,256,0,stream>>>(wih, wihW, 2*768*256);
  k_cvt<<<(2*768*256+255)/256,256,0,stream>>>(whh, whhW, 2*768*256);
  for(int li=0; li<2; ++li){
    k_cvtT<<<(512*256+255)/256,256,0,stream>>>(r1 + li*512*256, r1T + li*256*512, 512, 256);
    k_cvtT<<<(256*24+255)/256, 256,0,stream>>>(r2 + li*256*24,  r2T + li*24*256,  256, 24);
    k_cvtT<<<(256*256+255)/256,256,0,stream>>>(pj + li*256*256, pjT + li*256*256, 256, 256);
    k_cvtT<<<(256*512+255)/256,256,0,stream>>>(f1 + li*256*512, f1T + li*512*256, 256, 512);
    k_cvtT<<<(512*256+255)/256,256,0,stream>>>(f2 + li*512*256, f2T + li*256*512, 512, 256);
  }
  k_cvtT<<<(256*96+255)/256,256,0,stream>>>(hd, hdT, 256, 96);
  k_zeroflags<<<1,256,0,stream>>>((unsigned*)((char*)d_ws + OF_FLAGS));

  const int smem = 19168*4;
  hipFuncSetAttribute(reinterpret_cast<const void*>(ssr_main),
                      hipFuncAttributeMaxDynamicSharedMemorySize, smem);
  ssr_main<<<4*BB, 1024, smem, stream>>>(x, emb, pos, r1T, br1, r2T, br2, wihW, whhW, bih, bhh,
                                         pjT, bpj, g1, be1, f1T, bf1, f2T, bf2, g2, be2, go, bo,
                                         hdT, bhd, d_ws, out);
}

// Round 18
// 4892.006 us; speedup vs baseline: 1.0847x; 1.0847x over previous
//
#include <hip/hip_runtime.h>
#include <hip/hip_fp16.h>

typedef unsigned short u16;
typedef _Float16 f16x8 __attribute__((ext_vector_type(8)));
typedef float f32x4 __attribute__((ext_vector_type(4)));

#define VV   96
#define DD   256
#define NSL  24
#define HH   512
#define LL   2
#define BB   64
#define TT   128

// ---- workspace byte layout (after 3,481,600 B of f16 weights) ----
#define EXB    3489792u           // exchange region base
#define SBYT   45056u             // per-batch exchange stride
#define OF_R2P 0u                 // [2][4][24] f32
#define OF_PJP 1024u              // [2][4][256] f32
#define OF_F2P 9216u              // [2][4][256] f32
#define OF_SM  17408u             // [2][256] f32
#define OF_S16 19456u             // [2][24][128] dwords (f16 pairs)
#define OF_FLAGS (EXB + 64u*SBYT) // 256 u32

#define AG_ST(p,v) __hip_atomic_store((p),(v),__ATOMIC_RELAXED,__HIP_MEMORY_SCOPE_AGENT)
#define AG_LD(p)   __hip_atomic_load((p),__ATOMIC_RELAXED,__HIP_MEMORY_SCOPE_AGENT)

__device__ __forceinline__ u16 f2h(float f){ return __half_as_ushort(__float2half(f)); }
__device__ __forceinline__ float gelu_f(float x){ return 0.5f*x*(1.f+erff(x*0.70710678118654752f)); }
__device__ __forceinline__ float sigm_f(float x){ return 1.f/(1.f+__expf(-x)); }
__device__ __forceinline__ float tanh_f(float x){
  x = fminf(15.f, fmaxf(-15.f, x));
  float e2 = __expf(2.f*x);
  return (e2-1.f)/(e2+1.f);
}

__device__ __forceinline__ float dotg8(const u16* __restrict__ row, const float* __restrict__ v,
                                       int g, int iters){
  float acc = 0.f;
  #pragma unroll
  for(int it=0; it<iters; ++it){
    int k = (it*8 + g)*8;
    uint4 w = *(const uint4*)(row + k);
    float4 a  = *(const float4*)(v + k);
    float4 bq = *(const float4*)(v + k + 4);
    float2 f0 = __half22float2(*(const __half2*)&w.x);
    float2 f1 = __half22float2(*(const __half2*)&w.y);
    float2 f2_ = __half22float2(*(const __half2*)&w.z);
    float2 f3 = __half22float2(*(const __half2*)&w.w);
    acc += f0.x*a.x + f0.y*a.y + f1.x*a.z + f1.y*a.w;
    acc += f2_.x*bq.x + f2_.y*bq.y + f3.x*bq.z + f3.y*bq.w;
  }
  return acc;
}
__device__ __forceinline__ float dotg16(const u16* __restrict__ row, const float* __restrict__ v,
                                        int tl, int iters){
  float acc = 0.f;
  #pragma unroll
  for(int it=0; it<iters; ++it){
    int k = (it*16 + tl)*8;
    uint4 w = *(const uint4*)(row + k);
    float4 a  = *(const float4*)(v + k);
    float4 bq = *(const float4*)(v + k + 4);
    float2 f0 = __half22float2(*(const __half2*)&w.x);
    float2 f1 = __half22float2(*(const __half2*)&w.y);
    float2 f2_ = __half22float2(*(const __half2*)&w.z);
    float2 f3 = __half22float2(*(const __half2*)&w.w);
    acc += f0.x*a.x + f0.y*a.y + f1.x*a.z + f1.y*a.w;
    acc += f2_.x*bq.x + f2_.y*bq.y + f3.x*bq.z + f3.y*bq.w;
  }
  return acc;
}
__device__ __forceinline__ float red8(float a){
  a += __shfl_down(a,4,64); a += __shfl_down(a,2,64); a += __shfl_down(a,1,64);
  return a;
}
__device__ __forceinline__ float red16(float a){
  a += __shfl_down(a,8,64); a += __shfl_down(a,4,64);
  a += __shfl_down(a,2,64); a += __shfl_down(a,1,64);
  return a;
}

// Batched-poll 4-WG barrier (R13-proven): 3 independent peer loads per round.
__device__ __forceinline__ void syncq(unsigned* flags, int b, int c, unsigned ep, int tid){
  __syncthreads();
  if(tid==0){
    AG_ST(&flags[b*4+c], ep);
    const int p0=(c+1)&3, p1=(c+2)&3, p2=(c+3)&3;
    for(;;){
      unsigned a0 = AG_LD(&flags[b*4+p0]);
      unsigned a1 = AG_LD(&flags[b*4+p1]);
      unsigned a2 = AG_LD(&flags[b*4+p2]);
      if(a0>=ep && a1>=ep && a2>=ep) break;
      __builtin_amdgcn_s_sleep(2);
    }
  }
  __syncthreads();
}
// Split barrier (used ONLY for sync#1, as in R13).
__device__ __forceinline__ void syncq_arrive(unsigned* flags, int b, int c, unsigned ep, int tid){
  __syncthreads();                    // all prior payload stores drained
  if(tid==0) AG_ST(&flags[b*4+c], ep);
}
__device__ __forceinline__ void syncq_wait(unsigned* flags, int b, int c, unsigned ep, int tid){
  if(tid==0){
    const int p0=(c+1)&3, p1=(c+2)&3, p2=(c+3)&3;
    for(;;){
      unsigned a0 = AG_LD(&flags[b*4+p0]);
      unsigned a1 = AG_LD(&flags[b*4+p1]);
      unsigned a2 = AG_LD(&flags[b*4+p2]);
      if(a0>=ep && a1>=ep && a2>=ep) break;
      __builtin_amdgcn_s_sleep(2);
    }
  }
  __syncthreads();
}

// ---------- prep kernels ----------
__global__ void k_cvt(const float* __restrict__ s, u16* __restrict__ d, int n){
  int i = blockIdx.x*256 + threadIdx.x;
  if(i<n) d[i] = f2h(s[i]);
}
__global__ void k_cvtT(const float* __restrict__ s, u16* __restrict__ d, int K, int N){
  int i = blockIdx.x*256 + threadIdx.x;
  if(i < K*N){ int k = i/N, n = i - k*N; d[n*K + k] = f2h(s[i]); }
}
__global__ void k_zeroflags(unsigned* f){ f[threadIdx.x] = 0u; }

__global__ __launch_bounds__(1024, 4) void ssr_main(
    const int* __restrict__ x, const float* __restrict__ emb, const float* __restrict__ pos,
    const u16* __restrict__ r1T, const float* __restrict__ b_r1,
    const u16* __restrict__ r2T, const float* __restrict__ b_r2,
    const u16* __restrict__ wihW, const u16* __restrict__ whhW,
    const float* __restrict__ bih, const float* __restrict__ bhh,
    const u16* __restrict__ pjT, const float* __restrict__ b_pj,
    const float* __restrict__ g1, const float* __restrict__ be1,
    const u16* __restrict__ f1T, const float* __restrict__ b_f1,
    const u16* __restrict__ f2T, const float* __restrict__ b_f2,
    const float* __restrict__ g2, const float* __restrict__ be2,
    const float* __restrict__ go, const float* __restrict__ bo,
    const u16* __restrict__ hdT, const float* __restrict__ b_hd,
    void* __restrict__ wsraw,
    float* __restrict__ out)
{
  extern __shared__ float sm[];
  float* S_l   = sm;                  // [2][24][64] fp32 sharded slot state
  u16*  sbf    = (u16*)(sm + 3072);   // [32][264] f16 gathered full S
  float* gh_l  = sm + 7296;           // [24][200] f32 local gh (own e-set)
  float* gx_l  = sm + 12096;          // 192
  float* ctx   = sm + 12288;          // 512
  float* xv    = sm + 12800;          // 256
  float* xm    = sm + 13056;          // 256
  float* h1    = sm + 13312;          // 256
  float* hmid_l= sm + 13568;          // 64
  float* ff_l  = sm + 13632;          // 128
  float* sctx  = sm + 13760;          // 64
  float* alpha = sm + 13824;          // 32
  float* red   = sm + 13856;          // 64
  float* pc    = sm + 13920;          // 1024
  // total 14944 floats = 59776 B

  const int wgid = blockIdx.x;
  const int b = wgid & 63;
  const int c = wgid >> 6;           // d-quarter index 0..3
  const int tid = threadIdx.x;
  const int g = tid & 7,  gid = tid >> 3;   // 128 groups of 8
  const int tl = tid & 15, tm = tid >> 4;   // 64 teams of 16

  char* exb = (char*)wsraw + EXB + (size_t)b*SBYT;
  float*    ex_r2p = (float*)(exb + OF_R2P);
  float*    ex_pjp = (float*)(exb + OF_PJP);
  float*    ex_f2p = (float*)(exb + OF_F2P);
  float*    ex_sm  = (float*)(exb + OF_SM);
  unsigned* ex_s16 = (unsigned*)(exb + OF_S16);
  unsigned* flags  = (unsigned*)((char*)wsraw + OF_FLAGS);
  unsigned ep = 0;

  for(int i=tid;i<3072;i+=1024) S_l[i]=0.f;
  for(int i=tid;i<4224;i+=1024) ((float*)sbf)[i]=0.f;
  __syncthreads();

  for(int t=0;t<TT;++t){
    const int tok = x[b*TT + t];
    if(tid<DD) xv[tid] = emb[tok*DD+tid] + pos[t*DD+tid];
    __syncthreads();

    for(int li=0; li<LL; ++li){
      // ---- layer entry: gather full S (f16) + slotmean (published at t-1)
      if(t>0){
        for(int i=tid;i<3072;i+=1024){
          int s_=i>>7, dw=i&127;
          unsigned d32 = AG_LD(&ex_s16[li*3072+i]);
          *(unsigned*)(sbf + s_*264 + dw*2) = d32;
        }
        if(tid<DD) ctx[DD+tid] = AG_LD(&ex_sm[li*DD+tid]);
      } else {
        if(tid<DD) ctx[DD+tid] = 0.f;
      }
      if(tid<DD) ctx[tid] = xv[tid];
      __syncthreads();

      // ---- route1 (N-split): own 64 rows, K=512
      {
        const u16* row = r1T + (size_t)(li*DD + c*64 + tm)*(2*DD);
        float a = red16(dotg16(row, ctx, tl, 4));
        if(!tl) hmid_l[tm] = gelu_f(a + b_r1[li*DD + c*64 + tm]);
      }
      __syncthreads();
      // ---- route2 partials (own hmid slice) -> publish, then ARRIVE
      if(gid < NSL){
        const u16* row = r2T + (size_t)(li*NSL + gid)*DD + c*64;
        float a = red8(dotg8(row, hmid_l, g, 1));
        if(!g) AG_ST(&ex_r2p[li*96 + c*24 + gid], a);
      }
      ++ep;
      syncq_arrive(flags, b, c, ep, tid);     // r2 stores drained + flag up
      // ---- overlapped local work: gx + MFMA hides peer flag latency
      {
        const u16* W = wihW + (size_t)li*3*DD*DD;
        for(int le=gid; le<192; le+=128){
          int e = (le>>6)*DD + c*64 + (le&63);
          float a = red8(dotg8(W + (size_t)e*DD, xv, g, 4));
          if(!g) gx_l[le] = a;
        }
      }
      {
        const int lane = tid & 63, w = tid >> 6;
        if(w < 12){
          const int lr = lane & 15, lk = lane >> 4;
          const int q = w >> 2, j = w & 3;
          const u16* WB = whhW + (size_t)li*3*DD*DD;
          const u16* a0p = sbf + lr*264 + lk*8;
          const u16* a1p = sbf + (16+lr)*264 + lk*8;
          const u16* bp = WB + (size_t)(q*DD + c*64 + j*16 + lr)*DD + lk*8;
          f32x4 acc0 = {0.f,0.f,0.f,0.f}, acc1 = {0.f,0.f,0.f,0.f};
          #pragma unroll
          for(int ks=0; ks<8; ++ks){
            f16x8 bfr = *(const f16x8*)(bp + ks*32);
            f16x8 a0  = *(const f16x8*)(a0p + ks*32);
            f16x8 a1  = *(const f16x8*)(a1p + ks*32);
            acc0 = __builtin_amdgcn_mfma_f32_16x16x32_f16(a0, bfr, acc0, 0,0,0);
            acc1 = __builtin_amdgcn_mfma_f32_16x16x32_f16(a1, bfr, acc1, 0,0,0);
          }
          int le = q*64 + j*16 + lr;
          #pragma unroll
          for(int r=0;r<4;++r){
            int s0 = lk*4 + r;
            gh_l[s0*200 + le] = acc0[r];
            int s1 = 16 + lk*4 + r;
            if(s1 < NSL) gh_l[s1*200 + le] = acc1[r];
          }
        }
      }
      syncq_wait(flags, b, c, ep, tid);       // peers' r2 partials visible
      // ---- alpha: fused 32-lane gather + softmax (replicated-identical)
      if(tid < 32){
        float lg = -1e30f;
        if(tid < NSL){
          lg = b_r2[li*NSL+tid];
          #pragma unroll
          for(int cc=0;cc<4;++cc) lg += AG_LD(&ex_r2p[li*96 + cc*24 + tid]);
        }
        float m = lg;
        #pragma unroll
        for(int o=16;o>0;o>>=1) m = fmaxf(m, __shfl_xor(m,o,32));
        float e = (tid<NSL) ? __expf(lg-m) : 0.f;
        float s = e;
        #pragma unroll
        for(int o=16;o>0;o>>=1) s += __shfl_xor(s,o,32);
        if(tid<NSL) alpha[tid] = e/s;
      }
      __syncthreads();
      // ---- GRU update (own d-quarter, all 24 slots): all local
      {
        int dd = tid & 63, sg = tid >> 6;
        int dg = li*3*DD + c*64 + dd;
        float gir = gx_l[dd],      bir = bih[dg],        bhr = bhh[dg];
        float giz = gx_l[64+dd],   biz = bih[dg+DD],     bhz = bhh[dg+DD];
        float gin = gx_l[128+dd],  bin = bih[dg+2*DD],   bhn = bhh[dg+2*DD];
        float pctx = 0.f;
        float* Sll = S_l + li*NSL*64;
        #pragma unroll
        for(int h=0;h<2;++h){
          int s_ = sg + h*16;
          if(s_ < NSL){
            float al = alpha[s_];
            float hr = gh_l[s_*200 + dd]       + bhr;
            float hz = gh_l[s_*200 + 64 + dd]  + bhz;
            float hn = gh_l[s_*200 + 128 + dd] + bhn;
            float rr = sigm_f(al*gir + bir + hr);
            float zz = sigm_f(al*giz + biz + hz);
            float nn = tanh_f(al*gin + bin + rr*hn);
            float sv = Sll[s_*64+dd];
            float ns = (1.f-zz)*nn + zz*sv;
            Sll[s_*64+dd] = ns;
            pctx += al*ns;
          }
        }
        pc[tid] = pctx;
      }
      __syncthreads();
      if(tid<64){
        float s_=0.f;
        #pragma unroll
        for(int k=0;k<16;++k) s_ += pc[k*64+tid];
        sctx[tid] = s_;
        float m_=0.f;
        const float* Sll = S_l + li*NSL*64;
        #pragma unroll
        for(int s2=0;s2<NSL;++s2) m_ += Sll[s2*64+tid];
        AG_ST(&ex_sm[li*DD + c*64 + tid], m_*(1.f/NSL));
      }
      __syncthreads();
      // ---- publish S_new (f16 pairs) + proj partials  (R13 position)
      for(int i=tid;i<768;i+=1024){
        int s_ = i>>5, dp = (i&31)*2;
        const float* Sll = S_l + li*NSL*64;
        unsigned lo = (unsigned)f2h(Sll[s_*64+dp]);
        unsigned hi = (unsigned)f2h(Sll[s_*64+dp+1]);
        AG_ST(&ex_s16[li*3072 + s_*128 + c*32 + (i&31)], lo | (hi<<16));
      }
      {
        #pragma unroll
        for(int p=0;p<2;++p){
          int dout = p*128 + gid;
          const u16* row = pjT + (size_t)(li*DD + dout)*DD + c*64;
          float a = red8(dotg8(row, sctx, g, 1));
          if(!g) AG_ST(&ex_pjp[li*1024 + c*256 + dout], a);
        }
      }
      syncq(flags, b, c, ++ep, tid);          // S16, sm, proj partials
      // ---- fused xm + LN1 (2 barriers)
      {
        float v = 0.f;
        if(tid<DD){
          float s_ = b_pj[li*DD+tid];
          #pragma unroll
          for(int cc=0;cc<4;++cc) s_ += AG_LD(&ex_pjp[li*1024 + cc*256 + tid]);
          v = xv[tid] + s_;
          xm[tid] = v;
        }
        float s1 = (tid<DD)?v:0.f, s2 = (tid<DD)?v*v:0.f;
        #pragma unroll
        for(int o=32;o>0;o>>=1){ s1 += __shfl_xor(s1,o,64); s2 += __shfl_xor(s2,o,64); }
        if(tid<DD && (tid&63)==0){ red[tid>>6]=s1; red[8+(tid>>6)]=s2; }
        __syncthreads();
        if(tid<DD){
          float a = red[0]+red[1]+red[2]+red[3];
          float cs= red[8]+red[9]+red[10]+red[11];
          float m = a*(1.f/DD), rs = rsqrtf(cs*(1.f/DD) - m*m + 1e-5f);
          h1[tid] = (v-m)*rs*g1[li*DD+tid] + be1[li*DD+tid];
        }
        __syncthreads();
      }
      // ---- ffn1 (N-split, local): own 128 rows, K=256
      if(gid < 128){
        const u16* row = f1T + (size_t)(li*HH + c*128 + gid)*DD;
        float a = red8(dotg8(row, h1, g, 4));
        if(!g) ff_l[gid] = gelu_f(a + b_f1[li*HH + c*128 + gid]);
      }
      __syncthreads();
      // ---- ffn2 partials (K-split over own ff 128-slice)
      {
        #pragma unroll
        for(int p=0;p<4;++p){
          int dout = p*64 + tm;
          const u16* row = f2T + (size_t)(li*DD + dout)*HH + c*128;
          float a = red16(dotg16(row, ff_l, tl, 1));
          if(!tl) AG_ST(&ex_f2p[li*1024 + c*256 + dout], a);
        }
      }
      syncq(flags, b, c, ++ep, tid);          // ffn2 partials
      // ---- fused xm2 + LN2 -> xv (2 barriers)
      {
        float v = 0.f;
        if(tid<DD){
          float s_ = b_f2[li*DD+tid];
          #pragma unroll
          for(int cc=0;cc<4;++cc) s_ += AG_LD(&ex_f2p[li*1024 + cc*256 + tid]);
          v = xm[tid] + s_;
        }
        float s1 = (tid<DD)?v:0.f, s2 = (tid<DD)?v*v:0.f;
        #pragma unroll
        for(int o=32;o>0;o>>=1){ s1 += __shfl_xor(s1,o,64); s2 += __shfl_xor(s2,o,64); }
        if(tid<DD && (tid&63)==0){ red[tid>>6]=s1; red[8+(tid>>6)]=s2; }
        __syncthreads();
        if(tid<DD){
          float a = red[0]+red[1]+red[2]+red[3];
          float cs= red[8]+red[9]+red[10]+red[11];
          float m = a*(1.f/DD), rs = rsqrtf(cs*(1.f/DD) - m*m + 1e-5f);
          xv[tid] = (v-m)*rs*g2[li*DD+tid] + be2[li*DD+tid];
        }
        __syncthreads();
      }
    } // layers

    // ---- head: fused LN (2 barriers) + own 24 rows GEMV
    {
      float v = (tid<DD) ? xv[tid] : 0.f;
      float s1 = v, s2 = v*v;
      #pragma unroll
      for(int o=32;o>0;o>>=1){ s1 += __shfl_xor(s1,o,64); s2 += __shfl_xor(s2,o,64); }
      if(tid<DD && (tid&63)==0){ red[tid>>6]=s1; red[8+(tid>>6)]=s2; }
      __syncthreads();
      if(tid<DD){
        float a = red[0]+red[1]+red[2]+red[3];
        float cs= red[8]+red[9]+red[10]+red[11];
        float m = a*(1.f/DD), rs = rsqrtf(cs*(1.f/DD) - m*m + 1e-5f);
        h1[tid] = (v-m)*rs*go[tid] + bo[tid];
      }
      __syncthreads();
    }
    if(gid < NSL){
      int n = c*24 + gid;
      float acc = red8(dotg8(hdT + (size_t)n*DD, h1, g, 4));
      if(!g) out[((size_t)b*TT + t)*VV + n] = acc + b_hd[n];
    }
    __syncthreads();
  }
}

extern "C" void kernel_launch(void* const* d_in, const int* in_sizes, int n_in,
                              void* d_out, int out_size, void* d_ws, size_t ws_size,
                              hipStream_t stream){
  const int*   x    = (const int*)  d_in[0];
  const float* emb  = (const float*)d_in[1];
  const float* pos  = (const float*)d_in[2];
  const float* r1   = (const float*)d_in[3];
  const float* br1  = (const float*)d_in[4];
  const float* r2   = (const float*)d_in[5];
  const float* br2  = (const float*)d_in[6];
  const float* wih  = (const float*)d_in[7];
  const float* whh  = (const float*)d_in[8];
  const float* bih  = (const float*)d_in[9];
  const float* bhh  = (const float*)d_in[10];
  const float* pj   = (const float*)d_in[11];
  const float* bpj  = (const float*)d_in[12];
  const float* g1   = (const float*)d_in[13];
  const float* be1  = (const float*)d_in[14];
  const float* f1   = (const float*)d_in[15];
  const float* bf1  = (const float*)d_in[16];
  const float* f2   = (const float*)d_in[17];
  const float* bf2  = (const float*)d_in[18];
  const float* g2   = (const float*)d_in[19];
  const float* be2  = (const float*)d_in[20];
  const float* go   = (const float*)d_in[21];
  const float* bo   = (const float*)d_in[22];
  const float* hd   = (const float*)d_in[23];
  const float* bhd  = (const float*)d_in[24];
  float* out = (float*)d_out;
  u16* ws = (u16*)d_ws;

  // f16 weight sections in workspace (u16 element offsets)
  u16* r1T  = ws + 0;        // L*256*512
  u16* r2T  = ws + 262144;   // L*24*256
  u16* wihW = ws + 274432;   // L*768*256
  u16* whhW = ws + 667648;   // L*768*256
  u16* pjT  = ws + 1060864;  // L*256*256
  u16* f1T  = ws + 1191936;  // L*512*256
  u16* f2T  = ws + 1454080;  // L*256*512
  u16* hdT  = ws + 1716224;  // 96*256 -> weights end 3,481,600 B

  k_cvt<<<(2*768*256+255)/256,256,0,stream>>>(wih, wihW, 2*768*256);
  k_cvt<<<(2*768*256+255)/256,256,0,stream>>>(whh, whhW, 2*768*256);
  for(int li=0; li<2; ++li){
    k_cvtT<<<(512*256+255)/256,256,0,stream>>>(r1 + li*512*256, r1T + li*256*512, 512, 256);
    k_cvtT<<<(256*24+255)/256, 256,0,stream>>>(r2 + li*256*24,  r2T + li*24*256,  256, 24);
    k_cvtT<<<(256*256+255)/256,256,0,stream>>>(pj + li*256*256, pjT + li*256*256, 256, 256);
    k_cvtT<<<(256*512+255)/256,256,0,stream>>>(f1 + li*256*512, f1T + li*512*256, 256, 512);
    k_cvtT<<<(512*256+255)/256,256,0,stream>>>(f2 + li*512*256, f2T + li*256*512, 512, 256);
  }
  k_cvtT<<<(256*96+255)/256,256,0,stream>>>(hd, hdT, 256, 96);
  k_zeroflags<<<1,256,0,stream>>>((unsigned*)((char*)d_ws + OF_FLAGS));

  const int smem = 14944*4;
  hipFuncSetAttribute(reinterpret_cast<const void*>(ssr_main),
                      hipFuncAttributeMaxDynamicSharedMemorySize, smem);
  ssr_main<<<4*BB, 1024, smem, stream>>>(x, emb, pos, r1T, br1, r2T, br2, wihW, whhW, bih, bhh,
                                         pjT, bpj, g1, be1, f1T, bf1, f2T, bf2, g2, be2, go, bo,
                                         hdT, bhd, d_ws, out);
}